// Round 2
// baseline (1037.748 us; speedup 1.0000x reference)
//
#include <hip/hip_runtime.h>

#define DIM 1024
#define MROWS 16384
#define NLAYERS 18
#define RANK 32
#define GROUPSZ 16

typedef _Float16 f16_t;
typedef __attribute__((ext_vector_type(8))) _Float16 f16x8;
typedef __attribute__((ext_vector_type(4))) _Float16 f16x4;
typedef __attribute__((ext_vector_type(4))) float f32x4;

__device__ __forceinline__ float h2f(f16_t h) { return (float)h; }
__device__ __forceinline__ f16_t f2h(float f) { return (f16_t)f; }

// ---------------- W_eff = dequant(q,s) + lb@la  (fp16) ----------------
// grid: 18 layers * 64 row-tiles (16 rows each), 256 threads (4 cols each)
__global__ __launch_bounds__(256) void prep_weights(
    const int* __restrict__ qw, const float* __restrict__ scales,
    const float* __restrict__ la, const float* __restrict__ lb,
    f16_t* __restrict__ weff)
{
    const int blk = blockIdx.x;
    const int layer = blk >> 6;
    const int o0 = (blk & 63) * 16;
    const int t = threadIdx.x;
    __shared__ float lbs[16][32];
    {
        const float* src = lb + ((size_t)layer * DIM + o0) * RANK;
        for (int i = t; i < 16 * 32; i += 256) lbs[i >> 5][i & 31] = src[i];
    }
    __syncthreads();
    const int i0 = t * 4;
    float acc[16][4];
#pragma unroll
    for (int o = 0; o < 16; ++o)
#pragma unroll
        for (int k = 0; k < 4; ++k) acc[o][k] = 0.f;
    const float* lap = la + (size_t)layer * RANK * DIM + i0;
#pragma unroll 8
    for (int r = 0; r < RANK; ++r) {
        float4 a4 = *(const float4*)(lap + (size_t)r * DIM);
#pragma unroll
        for (int o = 0; o < 16; ++o) {
            float f = lbs[o][r];
            acc[o][0] += f * a4.x; acc[o][1] += f * a4.y;
            acc[o][2] += f * a4.z; acc[o][3] += f * a4.w;
        }
    }
    const size_t wbase = (size_t)layer * DIM * DIM;
#pragma unroll
    for (int o = 0; o < 16; ++o) {
        const int orow = o0 + o;
        const int4 q4 = *(const int4*)(qw + wbase + (size_t)orow * DIM + i0);
        const float s = scales[((size_t)layer * DIM + orow) * (DIM / GROUPSZ) + (i0 >> 4)];
        f16x4 w;
        w[0] = f2h((float)(q4.x - 8) * s + acc[o][0]);
        w[1] = f2h((float)(q4.y - 8) * s + acc[o][1]);
        w[2] = f2h((float)(q4.z - 8) * s + acc[o][2]);
        w[3] = f2h((float)(q4.w - 8) * s + acc[o][3]);
        *(f16x4*)(weff + wbase + (size_t)orow * DIM + i0) = w;
    }
}

// ---------------- fp32 -> fp16 convert ----------------
__global__ __launch_bounds__(256) void cvt_f32_f16(const float* __restrict__ in,
                                                   f16_t* __restrict__ out, int n)
{
    const int i = (blockIdx.x * 256 + threadIdx.x) * 4;
    if (i < n) {
        float4 v = *(const float4*)(in + i);
        f16x4 o;
        o[0] = f2h(v.x); o[1] = f2h(v.y); o[2] = f2h(v.z); o[3] = f2h(v.w);
        *(f16x4*)(out + i) = o;
    }
}

// ---------------- GEMM: C = A @ W^T, scaled epilogue ----------------
// A [M][1024] fp16 (scaled by a_in), W [1024][1024] fp16 row-major (= B^T).
// Epilogue: v = acc*sA + (bias + res)*sB   (res absent for EPI=0)
// EPI: 0 = relu -> fp16 out; 1 = +res -> fp16 out; 2 = +res -> fp32 out
template <int EPI>
__global__ __launch_bounds__(256, 2) void gemm_bt(
    const f16_t* __restrict__ A, const f16_t* __restrict__ W,
    const float* __restrict__ bias, const f16_t* __restrict__ res,
    f16_t* __restrict__ outb, float* __restrict__ outf,
    float sA, float sB)
{
    constexpr int BM = 128, BN = 128, BK = 64, K = DIM;
    __shared__ __align__(16) f16_t As[BM * BK];
    __shared__ __align__(16) f16_t Bs[BN * BK];
    const int t = threadIdx.x;
    const int m0 = blockIdx.y * BM;
    const int n0 = blockIdx.x * BN;
    const int wave = t >> 6, lane = t & 63;
    const int wr = wave >> 1, wc = wave & 1;
    const int lr = lane & 15;
    const int lk = (lane >> 4) * 8;

    f32x4 acc[4][4];
#pragma unroll
    for (int i = 0; i < 4; ++i)
#pragma unroll
        for (int j = 0; j < 4; ++j) acc[i][j] = (f32x4){0.f, 0.f, 0.f, 0.f};

    const int srow = t >> 3;          // 0..31
    const int scol = (t & 7) * 8;     // element col within K-tile
    const f16_t* Ag = A + (size_t)(m0 + srow) * K + scol;
    const f16_t* Wg = W + (size_t)(n0 + srow) * K + scol;
    f16_t* Asd = As + t * 8;
    f16_t* Bsd = Bs + t * 8;

    for (int kt = 0; kt < K / BK; ++kt) {
        __syncthreads();
        const int kb = kt * BK;
#pragma unroll
        for (int i = 0; i < 4; ++i) {
            __builtin_amdgcn_global_load_lds(
                (const __attribute__((address_space(1))) void*)(Ag + (size_t)(i * 32) * K + kb),
                (__attribute__((address_space(3))) void*)(Asd + i * 2048), 16, 0, 0);
        }
#pragma unroll
        for (int i = 0; i < 4; ++i) {
            __builtin_amdgcn_global_load_lds(
                (const __attribute__((address_space(1))) void*)(Wg + (size_t)(i * 32) * K + kb),
                (__attribute__((address_space(3))) void*)(Bsd + i * 2048), 16, 0, 0);
        }
        __syncthreads();
#pragma unroll
        for (int kk = 0; kk < BK / 32; ++kk) {
            f16x8 af[4], bfr[4];
#pragma unroll
            for (int fm = 0; fm < 4; ++fm)
                af[fm] = *(const f16x8*)&As[(wr * 64 + fm * 16 + lr) * BK + kk * 32 + lk];
#pragma unroll
            for (int fn = 0; fn < 4; ++fn)
                bfr[fn] = *(const f16x8*)&Bs[(wc * 64 + fn * 16 + lr) * BK + kk * 32 + lk];
#pragma unroll
            for (int fm = 0; fm < 4; ++fm)
#pragma unroll
                for (int fn = 0; fn < 4; ++fn)
                    acc[fm][fn] = __builtin_amdgcn_mfma_f32_16x16x32_f16(
                        af[fm], bfr[fn], acc[fm][fn], 0, 0, 0);
        }
    }

    // C/D layout: col = lane&15, row = (lane>>4)*4 + reg  [m89/m91]
    const int crow0 = m0 + wr * 64 + (lane >> 4) * 4;
    const int ccol0 = n0 + wc * 64;
#pragma unroll
    for (int fm = 0; fm < 4; ++fm) {
#pragma unroll
        for (int fn = 0; fn < 4; ++fn) {
            const int col = ccol0 + fn * 16 + lr;
            const float bcol = bias[col];
#pragma unroll
            for (int j = 0; j < 4; ++j) {
                const int row = crow0 + fm * 16 + j;
                float v;
                if (EPI == 0) {
                    v = acc[fm][fn][j] * sA + bcol * sB;
                    v = fmaxf(v, 0.f);
                    outb[(size_t)row * DIM + col] = f2h(v);
                } else {
                    const float rv = h2f(res[(size_t)row * DIM + col]);
                    v = acc[fm][fn][j] * sA + (bcol + rv) * sB;
                    if (EPI == 1) outb[(size_t)row * DIM + col] = f2h(v);
                    else          outf[(size_t)row * DIM + col] = v;
                }
            }
        }
    }
}

// ---------------- row LayerNorm (fp16 in/out, scale-invariant) ----------------
__global__ __launch_bounds__(256) void ln_kernel(const f16_t* __restrict__ in,
                                                 f16_t* __restrict__ out,
                                                 const float* __restrict__ gamma,
                                                 const float* __restrict__ beta)
{
    const int row = blockIdx.x;
    const int t = threadIdx.x;
    const int c = t * 4;
    f16x4 v4 = *(const f16x4*)(in + (size_t)row * DIM + c);
    float h0 = h2f(v4[0]), h1 = h2f(v4[1]), h2 = h2f(v4[2]), h3 = h2f(v4[3]);
    float s = h0 + h1 + h2 + h3;
    float sq = h0 * h0 + h1 * h1 + h2 * h2 + h3 * h3;
#pragma unroll
    for (int off = 32; off > 0; off >>= 1) {
        s += __shfl_down(s, off);
        sq += __shfl_down(sq, off);
    }
    __shared__ float ss[4], ssq[4];
    const int wave = t >> 6, lane = t & 63;
    if (lane == 0) { ss[wave] = s; ssq[wave] = sq; }
    __syncthreads();
    s = ss[0] + ss[1] + ss[2] + ss[3];
    sq = ssq[0] + ssq[1] + ssq[2] + ssq[3];
    const float mu = s * (1.f / DIM);
    const float var = sq * (1.f / DIM) - mu * mu;
    const float rs = rsqrtf(var + 1e-5f);
    float4 g = *(const float4*)(gamma + c);
    float4 b = *(const float4*)(beta + c);
    f16x4 o;
    o[0] = f2h((h0 - mu) * rs * g.x + b.x);
    o[1] = f2h((h1 - mu) * rs * g.y + b.y);
    o[2] = f2h((h2 - mu) * rs * g.z + b.z);
    o[3] = f2h((h3 - mu) * rs * g.w + b.w);
    *(f16x4*)(out + (size_t)row * DIM + c) = o;
}

extern "C" void kernel_launch(void* const* d_in, const int* in_sizes, int n_in,
                              void* d_out, int out_size, void* d_ws, size_t ws_size,
                              hipStream_t stream)
{
    const float* x      = (const float*)d_in[0];
    const int* qw       = (const int*)d_in[1];
    const float* scales = (const float*)d_in[2];
    const float* bias   = (const float*)d_in[3];
    const float* la     = (const float*)d_in[4];
    const float* lb     = (const float*)d_in[5];
    const float* g      = (const float*)d_in[6];
    const float* be     = (const float*)d_in[7];
    float* out = (float*)d_out;

    char* ws = (char*)d_ws;
    const size_t WEFF_BYTES = (size_t)NLAYERS * DIM * DIM * 2;  // 37.75 MB
    const size_t ACT_BYTES  = (size_t)MROWS * DIM * 2;          // 33.55 MB
    f16_t* weff = (f16_t*)ws;
    f16_t* hbuf = (f16_t*)(ws + WEFF_BYTES);
    f16_t* t1   = (f16_t*)(ws + WEFF_BYTES + ACT_BYTES);
    f16_t* t2   = (f16_t*)(ws + WEFF_BYTES + 2 * ACT_BYTES);

    prep_weights<<<dim3(NLAYERS * 64), 256, 0, stream>>>(qw, scales, la, lb, weff);
    cvt_f32_f16<<<dim3((MROWS * DIM) / 1024), 256, 0, stream>>>(x, hbuf, MROWS * DIM);

    // scale schedule (exact via ReLU homogeneity + LN scale-invariance):
    //   a1 = (1/16)  * relu(u1)        : sA=1/16,  sB=1/16
    //   a2 = (1/1024)* relu(u2)        : sA=1/64,  sB=1/1024
    //   z  = (1/1024)* (u3 + b + h0)   : sA=1,     sB=1/1024   (LN input)
    //   out=           u3 + b + h0     : sA=1024,  sB=1        (final fp32)
    const dim3 ggrid(DIM / 128, MROWS / 128);
    for (int blk = 0; blk < 6; ++blk) {
        const int li = blk * 3;
        const size_t w0 = (size_t)li * DIM * DIM;
        gemm_bt<0><<<ggrid, 256, 0, stream>>>(hbuf, weff + w0, bias + (size_t)li * DIM,
                                              nullptr, t1, nullptr, 1.f / 16.f, 1.f / 16.f);
        gemm_bt<0><<<ggrid, 256, 0, stream>>>(t1, weff + w0 + (size_t)DIM * DIM,
                                              bias + (size_t)(li + 1) * DIM, nullptr, t2, nullptr,
                                              1.f / 64.f, 1.f / 1024.f);
        if (blk < 5) {
            gemm_bt<1><<<ggrid, 256, 0, stream>>>(t2, weff + w0 + 2 * (size_t)DIM * DIM,
                                                  bias + (size_t)(li + 2) * DIM, hbuf, t1, nullptr,
                                                  1.f, 1.f / 1024.f);
            ln_kernel<<<dim3(MROWS), 256, 0, stream>>>(t1, hbuf, g + (size_t)blk * DIM,
                                                       be + (size_t)blk * DIM);
        } else {
            gemm_bt<2><<<ggrid, 256, 0, stream>>>(t2, weff + w0 + 2 * (size_t)DIM * DIM,
                                                  bias + (size_t)(li + 2) * DIM, hbuf, nullptr, out,
                                                  1024.f, 1.f);
        }
    }
}

// Round 3
// 1009.905 us; speedup vs baseline: 1.0276x; 1.0276x over previous
//
#include <hip/hip_runtime.h>

#define DIM 1024
#define MROWS 16384
#define NLAYERS 18
#define RANK 32
#define GROUPSZ 16

typedef _Float16 f16_t;
typedef __attribute__((ext_vector_type(8))) _Float16 f16x8;
typedef __attribute__((ext_vector_type(4))) _Float16 f16x4;
typedef __attribute__((ext_vector_type(4))) float f32x4;

__device__ __forceinline__ float h2f(f16_t h) { return (float)h; }
__device__ __forceinline__ f16_t f2h(float f) { return (f16_t)f; }

// ---------------- W_eff = dequant(q,s) + lb@la  (fp16) ----------------
// grid: 18 layers * 256 row-tiles (4 rows each), 256 threads (4 cols each)
__global__ __launch_bounds__(256) void prep_weights(
    const int* __restrict__ qw, const float* __restrict__ scales,
    const float* __restrict__ la, const float* __restrict__ lb,
    f16_t* __restrict__ weff)
{
    const int blk = blockIdx.x;
    const int layer = blk >> 8;
    const int o0 = (blk & 255) * 4;
    const int t = threadIdx.x;
    __shared__ float lbs[4][32];
    if (t < 128) {
        lbs[t >> 5][t & 31] = lb[((size_t)layer * DIM + o0) * RANK + t];
    }
    __syncthreads();
    const int i0 = t * 4;
    float acc[4][4];
#pragma unroll
    for (int o = 0; o < 4; ++o)
#pragma unroll
        for (int k = 0; k < 4; ++k) acc[o][k] = 0.f;
    const float* lap = la + (size_t)layer * RANK * DIM + i0;
#pragma unroll 8
    for (int r = 0; r < RANK; ++r) {
        float4 a4 = *(const float4*)(lap + (size_t)r * DIM);
#pragma unroll
        for (int o = 0; o < 4; ++o) {
            float f = lbs[o][r];
            acc[o][0] += f * a4.x; acc[o][1] += f * a4.y;
            acc[o][2] += f * a4.z; acc[o][3] += f * a4.w;
        }
    }
    const size_t wbase = (size_t)layer * DIM * DIM;
#pragma unroll
    for (int o = 0; o < 4; ++o) {
        const int orow = o0 + o;
        const int4 q4 = *(const int4*)(qw + wbase + (size_t)orow * DIM + i0);
        const float s = scales[((size_t)layer * DIM + orow) * (DIM / GROUPSZ) + (i0 >> 4)];
        f16x4 w;
        w[0] = f2h((float)(q4.x - 8) * s + acc[o][0]);
        w[1] = f2h((float)(q4.y - 8) * s + acc[o][1]);
        w[2] = f2h((float)(q4.z - 8) * s + acc[o][2]);
        w[3] = f2h((float)(q4.w - 8) * s + acc[o][3]);
        *(f16x4*)(weff + wbase + (size_t)orow * DIM + i0) = w;
    }
}

// ---------------- fp32 -> fp16 convert ----------------
__global__ __launch_bounds__(256) void cvt_f32_f16(const float* __restrict__ in,
                                                   f16_t* __restrict__ out, int n)
{
    const int i = (blockIdx.x * 256 + threadIdx.x) * 4;
    if (i < n) {
        float4 v = *(const float4*)(in + i);
        f16x4 o;
        o[0] = f2h(v.x); o[1] = f2h(v.y); o[2] = f2h(v.z); o[3] = f2h(v.w);
        *(f16x4*)(out + i) = o;
    }
}

// ---------------- GEMM: C = A @ W^T, scaled epilogue ----------------
// BM=256 BN=128 BK=64, 512 threads (8 waves, 4m x 2n), per-wave 64x64.
// Triple-buffered LDS, depth-2 prefetch, counted vmcnt(6), 1 raw barrier/K-tile.
// LDS rows XOR-swizzled (both-sides: pre-swizzled global source + swizzled ds_read).
// EPI: 0 = relu -> fp16 out; 1 = +res -> fp16 out; 2 = +res -> fp32 out
template <int EPI>
__global__ __launch_bounds__(512, 1) void gemm_bt(
    const f16_t* __restrict__ A, const f16_t* __restrict__ W,
    const float* __restrict__ bias, const f16_t* __restrict__ res,
    f16_t* __restrict__ outb, float* __restrict__ outf,
    float sA, float sB)
{
    constexpr int BM = 256, BN = 128, BK = 64, K = DIM;
    constexpr int KT = K / BK;  // 16
    __shared__ __align__(16) f16_t As[3][BM * BK];  // 3 x 32 KB
    __shared__ __align__(16) f16_t Bs[3][BN * BK];  // 3 x 16 KB  -> 144 KB

    const int tid = threadIdx.x;
    // XCD-chunked bijective swizzle (512 % 8 == 0): each XCD gets 64
    // consecutive tiles = 8 full M-bands -> A-band L2 locality.
    const int bid = blockIdx.x;
    const int nid = ((bid & 7) << 6) + (bid >> 3);
    const int m0 = (nid >> 3) * BM;
    const int n0 = (nid & 7) * BN;

    const int wave = tid >> 6, lane = tid & 63;
    const int wm = wave >> 1, wn = wave & 1;
    const int lr = lane & 15;
    const int l4 = lane >> 4;  // 0..3

    f32x4 acc[4][4];
#pragma unroll
    for (int i = 0; i < 4; ++i)
#pragma unroll
        for (int j = 0; j < 4; ++j) acc[i][j] = (f32x4){0.f, 0.f, 0.f, 0.f};

    // staging: thread tid stages row rs=tid>>3 (+i*64), 16B chunk (tid&7).
    // LDS dest is linear; source column chunk pre-swizzled: c_log = (tid&7)^(rs&7).
    const int rs = tid >> 3;                       // 0..63
    const int cs = ((tid & 7) ^ (rs & 7)) * 8;     // source col elems within K-tile
    const f16_t* Ag = A + (size_t)(m0 + rs) * K + cs;
    const f16_t* Wg = W + (size_t)(n0 + rs) * K + cs;

#define STAGE(kt_, buf_)                                                          \
    {                                                                             \
        const int kb_ = (kt_) * BK;                                               \
        f16_t* ad_ = &As[buf_][0] + tid * 8;                                      \
        f16_t* bd_ = &Bs[buf_][0] + tid * 8;                                      \
        _Pragma("unroll")                                                         \
        for (int i_ = 0; i_ < 4; ++i_)                                            \
            __builtin_amdgcn_global_load_lds(                                     \
                (const __attribute__((address_space(1))) void*)(Ag + (size_t)(i_ * 64) * K + kb_), \
                (__attribute__((address_space(3))) void*)(ad_ + i_ * 4096), 16, 0, 0); \
        _Pragma("unroll")                                                         \
        for (int i_ = 0; i_ < 2; ++i_)                                            \
            __builtin_amdgcn_global_load_lds(                                     \
                (const __attribute__((address_space(1))) void*)(Wg + (size_t)(i_ * 64) * K + kb_), \
                (__attribute__((address_space(3))) void*)(bd_ + i_ * 4096), 16, 0, 0); \
    }

    STAGE(0, 0);
    STAGE(1, 1);

    for (int kt = 0; kt < KT; ++kt) {
        if (kt < KT - 1) asm volatile("s_waitcnt vmcnt(6)" ::: "memory");
        else             asm volatile("s_waitcnt vmcnt(0)" ::: "memory");
        __builtin_amdgcn_s_barrier();
        if (kt + 2 < KT) STAGE(kt + 2, (kt + 2) % 3);

        const f16_t* ab = &As[kt % 3][0];
        const f16_t* bb = &Bs[kt % 3][0];
#pragma unroll
        for (int kk = 0; kk < 2; ++kk) {
            const int chunk = ((kk * 4 + l4) ^ (lr & 7)) * 8;  // swizzled ds_read
            f16x8 af[4], bfr[4];
#pragma unroll
            for (int fm = 0; fm < 4; ++fm)
                af[fm] = *(const f16x8*)&ab[(wm * 64 + fm * 16 + lr) * BK + chunk];
#pragma unroll
            for (int fn = 0; fn < 4; ++fn)
                bfr[fn] = *(const f16x8*)&bb[(wn * 64 + fn * 16 + lr) * BK + chunk];
            __builtin_amdgcn_s_setprio(1);
#pragma unroll
            for (int fm = 0; fm < 4; ++fm)
#pragma unroll
                for (int fn = 0; fn < 4; ++fn)
                    acc[fm][fn] = __builtin_amdgcn_mfma_f32_16x16x32_f16(
                        af[fm], bfr[fn], acc[fm][fn], 0, 0, 0);
            __builtin_amdgcn_s_setprio(0);
        }
    }
#undef STAGE

    // C/D layout: col = lane&15, row = (lane>>4)*4 + reg  [m89/m91]
    const int crow0 = m0 + wm * 64 + l4 * 4;
    const int ccol0 = n0 + wn * 64;
#pragma unroll
    for (int fm = 0; fm < 4; ++fm) {
#pragma unroll
        for (int fn = 0; fn < 4; ++fn) {
            const int col = ccol0 + fn * 16 + lr;
            const float bcol = bias[col];
#pragma unroll
            for (int j = 0; j < 4; ++j) {
                const int row = crow0 + fm * 16 + j;
                float v;
                if (EPI == 0) {
                    v = acc[fm][fn][j] * sA + bcol * sB;
                    v = fmaxf(v, 0.f);
                    outb[(size_t)row * DIM + col] = f2h(v);
                } else {
                    const float rv = h2f(res[(size_t)row * DIM + col]);
                    v = acc[fm][fn][j] * sA + (bcol + rv) * sB;
                    if (EPI == 1) outb[(size_t)row * DIM + col] = f2h(v);
                    else          outf[(size_t)row * DIM + col] = v;
                }
            }
        }
    }
}

// ---------------- row LayerNorm (fp16 in/out, scale-invariant) ----------------
__global__ __launch_bounds__(256) void ln_kernel(const f16_t* __restrict__ in,
                                                 f16_t* __restrict__ out,
                                                 const float* __restrict__ gamma,
                                                 const float* __restrict__ beta)
{
    const int row = blockIdx.x;
    const int t = threadIdx.x;
    const int c = t * 4;
    f16x4 v4 = *(const f16x4*)(in + (size_t)row * DIM + c);
    float h0 = h2f(v4[0]), h1 = h2f(v4[1]), h2 = h2f(v4[2]), h3 = h2f(v4[3]);
    float s = h0 + h1 + h2 + h3;
    float sq = h0 * h0 + h1 * h1 + h2 * h2 + h3 * h3;
#pragma unroll
    for (int off = 32; off > 0; off >>= 1) {
        s += __shfl_down(s, off);
        sq += __shfl_down(sq, off);
    }
    __shared__ float ss[4], ssq[4];
    const int wave = t >> 6, lane = t & 63;
    if (lane == 0) { ss[wave] = s; ssq[wave] = sq; }
    __syncthreads();
    s = ss[0] + ss[1] + ss[2] + ss[3];
    sq = ssq[0] + ssq[1] + ssq[2] + ssq[3];
    const float mu = s * (1.f / DIM);
    const float var = sq * (1.f / DIM) - mu * mu;
    const float rs = rsqrtf(var + 1e-5f);
    float4 g = *(const float4*)(gamma + c);
    float4 b = *(const float4*)(beta + c);
    f16x4 o;
    o[0] = f2h((h0 - mu) * rs * g.x + b.x);
    o[1] = f2h((h1 - mu) * rs * g.y + b.y);
    o[2] = f2h((h2 - mu) * rs * g.z + b.z);
    o[3] = f2h((h3 - mu) * rs * g.w + b.w);
    *(f16x4*)(out + (size_t)row * DIM + c) = o;
}

extern "C" void kernel_launch(void* const* d_in, const int* in_sizes, int n_in,
                              void* d_out, int out_size, void* d_ws, size_t ws_size,
                              hipStream_t stream)
{
    const float* x      = (const float*)d_in[0];
    const int* qw       = (const int*)d_in[1];
    const float* scales = (const float*)d_in[2];
    const float* bias   = (const float*)d_in[3];
    const float* la     = (const float*)d_in[4];
    const float* lb     = (const float*)d_in[5];
    const float* g      = (const float*)d_in[6];
    const float* be     = (const float*)d_in[7];
    float* out = (float*)d_out;

    char* ws = (char*)d_ws;
    const size_t WEFF_BYTES = (size_t)NLAYERS * DIM * DIM * 2;  // 37.75 MB
    const size_t ACT_BYTES  = (size_t)MROWS * DIM * 2;          // 33.55 MB
    f16_t* weff = (f16_t*)ws;
    f16_t* hbuf = (f16_t*)(ws + WEFF_BYTES);
    f16_t* t1   = (f16_t*)(ws + WEFF_BYTES + ACT_BYTES);
    f16_t* t2   = (f16_t*)(ws + WEFF_BYTES + 2 * ACT_BYTES);

    prep_weights<<<dim3(NLAYERS * 256), 256, 0, stream>>>(qw, scales, la, lb, weff);
    cvt_f32_f16<<<dim3((MROWS * DIM) / 1024), 256, 0, stream>>>(x, hbuf, MROWS * DIM);

    // scale schedule (exact via ReLU homogeneity + LN scale-invariance):
    //   a1 = (1/16)  * relu(u1)        : sA=1/16,  sB=1/16
    //   a2 = (1/1024)* relu(u2)        : sA=1/64,  sB=1/1024
    //   z  = (1/1024)* (u3 + b + h0)   : sA=1,     sB=1/1024   (LN input)
    //   out=           u3 + b + h0     : sA=1024,  sB=1        (final fp32)
    const dim3 ggrid(512);  // (M/256) * (N/128)
    for (int blk = 0; blk < 6; ++blk) {
        const int li = blk * 3;
        const size_t w0 = (size_t)li * DIM * DIM;
        gemm_bt<0><<<ggrid, 512, 0, stream>>>(hbuf, weff + w0, bias + (size_t)li * DIM,
                                              nullptr, t1, nullptr, 1.f / 16.f, 1.f / 16.f);
        gemm_bt<0><<<ggrid, 512, 0, stream>>>(t1, weff + w0 + (size_t)DIM * DIM,
                                              bias + (size_t)(li + 1) * DIM, nullptr, t2, nullptr,
                                              1.f / 64.f, 1.f / 1024.f);
        if (blk < 5) {
            gemm_bt<1><<<ggrid, 512, 0, stream>>>(t2, weff + w0 + 2 * (size_t)DIM * DIM,
                                                  bias + (size_t)(li + 2) * DIM, hbuf, t1, nullptr,
                                                  1.f, 1.f / 1024.f);
            ln_kernel<<<dim3(MROWS), 256, 0, stream>>>(t1, hbuf, g + (size_t)blk * DIM,
                                                       be + (size_t)blk * DIM);
        } else {
            gemm_bt<2><<<ggrid, 512, 0, stream>>>(t2, weff + w0 + 2 * (size_t)DIM * DIM,
                                                  bias + (size_t)(li + 2) * DIM, hbuf, nullptr, out,
                                                  1024.f, 1.f);
        }
    }
}

// Round 4
// 859.850 us; speedup vs baseline: 1.2069x; 1.1745x over previous
//
#include <hip/hip_runtime.h>

#define DIM 1024
#define MROWS 16384
#define NLAYERS 18
#define RANK 32
#define GROUPSZ 16

typedef _Float16 f16_t;
typedef __attribute__((ext_vector_type(8))) _Float16 f16x8;
typedef __attribute__((ext_vector_type(4))) _Float16 f16x4;
typedef __attribute__((ext_vector_type(4))) float f32x4;

__device__ __forceinline__ float h2f(f16_t h) { return (float)h; }
__device__ __forceinline__ f16_t f2h(float f) { return (f16_t)f; }

// ---------------- W_eff = dequant(q,s) + lb@la  (fp16) ----------------
// grid: 18 layers * 128 row-tiles (8 rows each), 256 threads (4 cols each)
__global__ __launch_bounds__(256) void prep_weights(
    const int* __restrict__ qw, const float* __restrict__ scales,
    const float* __restrict__ la, const float* __restrict__ lb,
    f16_t* __restrict__ weff)
{
    const int blk = blockIdx.x;
    const int layer = blk >> 7;
    const int o0 = (blk & 127) * 8;
    const int t = threadIdx.x;
    __shared__ float lbs[8][32];
    lbs[t >> 5][t & 31] = lb[((size_t)layer * DIM + o0) * RANK + t];
    __syncthreads();
    const int i0 = t * 4;
    float acc[8][4];
#pragma unroll
    for (int o = 0; o < 8; ++o)
#pragma unroll
        for (int k = 0; k < 4; ++k) acc[o][k] = 0.f;
    const float* lap = la + (size_t)layer * RANK * DIM + i0;
#pragma unroll 4
    for (int r = 0; r < RANK; ++r) {
        float4 a4 = *(const float4*)(lap + (size_t)r * DIM);
#pragma unroll
        for (int o = 0; o < 8; ++o) {
            float f = lbs[o][r];
            acc[o][0] += f * a4.x; acc[o][1] += f * a4.y;
            acc[o][2] += f * a4.z; acc[o][3] += f * a4.w;
        }
    }
    const size_t wbase = (size_t)layer * DIM * DIM;
#pragma unroll
    for (int o = 0; o < 8; ++o) {
        const int orow = o0 + o;
        const int4 q4 = *(const int4*)(qw + wbase + (size_t)orow * DIM + i0);
        const float s = scales[((size_t)layer * DIM + orow) * (DIM / GROUPSZ) + (i0 >> 4)];
        f16x4 w;
        w[0] = f2h((float)(q4.x - 8) * s + acc[o][0]);
        w[1] = f2h((float)(q4.y - 8) * s + acc[o][1]);
        w[2] = f2h((float)(q4.z - 8) * s + acc[o][2]);
        w[3] = f2h((float)(q4.w - 8) * s + acc[o][3]);
        *(f16x4*)(weff + wbase + (size_t)orow * DIM + i0) = w;
    }
}

// ---------------- fp32 -> fp16 convert ----------------
__global__ __launch_bounds__(256) void cvt_f32_f16(const float* __restrict__ in,
                                                   f16_t* __restrict__ out, int n)
{
    const int i = (blockIdx.x * 256 + threadIdx.x) * 4;
    if (i < n) {
        float4 v = *(const float4*)(in + i);
        f16x4 o;
        o[0] = f2h(v.x); o[1] = f2h(v.y); o[2] = f2h(v.z); o[3] = f2h(v.w);
        *(f16x4*)(out + i) = o;
    }
}

// ---------------- GEMM: C = A @ W^T, scaled epilogue ----------------
// BM=256 BN=256 BK=64, 512 threads (8 waves, 2m x 4n), per-wave 128x64.
// Double-buffered LDS (128 KB), counted vmcnt(8) (no in-loop drain),
// stage(kt+2) after the end-barrier. Grid = 256 blocks = exactly 1/CU.
// LDS chunk XOR-swizzle (pre-swizzled global src + swizzled ds_read; 0-conflict).
// EPI: 0 = relu -> fp16 out; 1 = +res -> fp16 out; 2 = +res -> fp32 out
template <int EPI>
__global__ __launch_bounds__(512, 1) void gemm_bt(
    const f16_t* __restrict__ A, const f16_t* __restrict__ W,
    const float* __restrict__ bias, const f16_t* __restrict__ res,
    f16_t* __restrict__ outb, float* __restrict__ outf,
    float sA, float sB)
{
    constexpr int BM = 256, BN = 256, BK = 64, K = DIM;
    constexpr int KT = K / BK;  // 16
    __shared__ __align__(16) f16_t As[2][BM * BK];  // 2 x 32 KB
    __shared__ __align__(16) f16_t Bs[2][BN * BK];  // 2 x 32 KB -> 128 KB

    const int tid = threadIdx.x;
    // 256 blocks, 8 XCDs -> 32 consecutive nids per XCD = 8 full M-bands
    // (4 col-tiles each) -> A-band fetched from HBM once per XCD.
    const int bid = blockIdx.x;
    const int nid = ((bid & 7) << 5) + (bid >> 3);
    const int m0 = (nid >> 2) * BM;
    const int n0 = (nid & 3) * BN;

    const int wave = tid >> 6, lane = tid & 63;
    const int wm = wave >> 2;  // 0..1
    const int wn = wave & 3;   // 0..3
    const int lr = lane & 15;
    const int l4 = lane >> 4;  // 0..3

    f32x4 acc[8][4];
#pragma unroll
    for (int i = 0; i < 8; ++i)
#pragma unroll
        for (int j = 0; j < 4; ++j) acc[i][j] = (f32x4){0.f, 0.f, 0.f, 0.f};

    // staging: thread t round j stages row j*64 + (t>>3), 16B chunk (t&7).
    // LDS dest linear; global source chunk pre-swizzled: c_src = (t&7)^(row&7).
    const int rs = tid >> 3;                       // 0..63
    const int cs = ((tid & 7) ^ (rs & 7)) * 8;     // src col elems in K-tile
    const f16_t* Ag = A + (size_t)(m0 + rs) * K + cs;
    const f16_t* Wg = W + (size_t)(n0 + rs) * K + cs;

#define STAGE(kt_, buf_)                                                          \
    {                                                                             \
        const int kb_ = (kt_) * BK;                                               \
        f16_t* ad_ = &As[buf_][0] + tid * 8;                                      \
        f16_t* bd_ = &Bs[buf_][0] + tid * 8;                                      \
        _Pragma("unroll")                                                         \
        for (int j_ = 0; j_ < 4; ++j_)                                            \
            __builtin_amdgcn_global_load_lds(                                     \
                (const __attribute__((address_space(1))) void*)(Ag + (size_t)(j_ * 64) * K + kb_), \
                (__attribute__((address_space(3))) void*)(ad_ + j_ * 4096), 16, 0, 0); \
        _Pragma("unroll")                                                         \
        for (int j_ = 0; j_ < 4; ++j_)                                            \
            __builtin_amdgcn_global_load_lds(                                     \
                (const __attribute__((address_space(1))) void*)(Wg + (size_t)(j_ * 64) * K + kb_), \
                (__attribute__((address_space(3))) void*)(bd_ + j_ * 4096), 16, 0, 0); \
    }

    STAGE(0, 0);
    STAGE(1, 1);

    for (int kt = 0; kt < KT; ++kt) {
        // counted wait: the 8 newest outstanding loads are STAGE(kt+1);
        // vmcnt(8) guarantees STAGE(kt) retired (FIFO). Never drains in-loop.
        if (kt < KT - 1) asm volatile("s_waitcnt vmcnt(8)" ::: "memory");
        else             asm volatile("s_waitcnt vmcnt(0)" ::: "memory");
        __builtin_amdgcn_s_barrier();

        const f16_t* ab = &As[kt & 1][0];
        const f16_t* bb = &Bs[kt & 1][0];
#pragma unroll
        for (int kk = 0; kk < 2; ++kk) {
            f16x8 bfr[4];
#pragma unroll
            for (int fn = 0; fn < 4; ++fn) {
                const int row = wn * 64 + fn * 16 + lr;
                const int chunk = ((kk * 4 + l4) ^ (row & 7)) * 8;
                bfr[fn] = *(const f16x8*)&bb[row * BK + chunk];
            }
            f16x8 af[8];
#pragma unroll
            for (int fm = 0; fm < 8; ++fm) {
                const int row = wm * 128 + fm * 16 + lr;
                const int chunk = ((kk * 4 + l4) ^ (row & 7)) * 8;
                af[fm] = *(const f16x8*)&ab[row * BK + chunk];
            }
            __builtin_amdgcn_s_setprio(1);
#pragma unroll
            for (int fm = 0; fm < 8; ++fm)
#pragma unroll
                for (int fn = 0; fn < 4; ++fn)
                    acc[fm][fn] = __builtin_amdgcn_mfma_f32_16x16x32_f16(
                        af[fm], bfr[fn], acc[fm][fn], 0, 0, 0);
            __builtin_amdgcn_s_setprio(0);
        }
        __builtin_amdgcn_s_barrier();  // all reads of buf[kt&1] done
        if (kt + 2 < KT) STAGE(kt + 2, kt & 1);
    }
#undef STAGE

    // C/D layout: col = lane&15, row = (lane>>4)*4 + reg  [m89/m91]
    const int crow0 = m0 + wm * 128 + l4 * 4;
    const int ccol0 = n0 + wn * 64;
#pragma unroll
    for (int fm = 0; fm < 8; ++fm) {
#pragma unroll
        for (int fn = 0; fn < 4; ++fn) {
            const int col = ccol0 + fn * 16 + lr;
            const float bcol = bias[col];
#pragma unroll
            for (int j = 0; j < 4; ++j) {
                const int row = crow0 + fm * 16 + j;
                float v;
                if (EPI == 0) {
                    v = acc[fm][fn][j] * sA + bcol * sB;
                    v = fmaxf(v, 0.f);
                    outb[(size_t)row * DIM + col] = f2h(v);
                } else {
                    const float rv = h2f(res[(size_t)row * DIM + col]);
                    v = acc[fm][fn][j] * sA + (bcol + rv) * sB;
                    if (EPI == 1) outb[(size_t)row * DIM + col] = f2h(v);
                    else          outf[(size_t)row * DIM + col] = v;
                }
            }
        }
    }
}

// ---------------- row LayerNorm (fp16 in/out, scale-invariant) ----------------
__global__ __launch_bounds__(256) void ln_kernel(const f16_t* __restrict__ in,
                                                 f16_t* __restrict__ out,
                                                 const float* __restrict__ gamma,
                                                 const float* __restrict__ beta)
{
    const int row = blockIdx.x;
    const int t = threadIdx.x;
    const int c = t * 4;
    f16x4 v4 = *(const f16x4*)(in + (size_t)row * DIM + c);
    float h0 = h2f(v4[0]), h1 = h2f(v4[1]), h2 = h2f(v4[2]), h3 = h2f(v4[3]);
    float s = h0 + h1 + h2 + h3;
    float sq = h0 * h0 + h1 * h1 + h2 * h2 + h3 * h3;
#pragma unroll
    for (int off = 32; off > 0; off >>= 1) {
        s += __shfl_down(s, off);
        sq += __shfl_down(sq, off);
    }
    __shared__ float ss[4], ssq[4];
    const int wave = t >> 6, lane = t & 63;
    if (lane == 0) { ss[wave] = s; ssq[wave] = sq; }
    __syncthreads();
    s = ss[0] + ss[1] + ss[2] + ss[3];
    sq = ssq[0] + ssq[1] + ssq[2] + ssq[3];
    const float mu = s * (1.f / DIM);
    const float var = sq * (1.f / DIM) - mu * mu;
    const float rs = rsqrtf(var + 1e-5f);
    float4 g = *(const float4*)(gamma + c);
    float4 b = *(const float4*)(beta + c);
    f16x4 o;
    o[0] = f2h((h0 - mu) * rs * g.x + b.x);
    o[1] = f2h((h1 - mu) * rs * g.y + b.y);
    o[2] = f2h((h2 - mu) * rs * g.z + b.z);
    o[3] = f2h((h3 - mu) * rs * g.w + b.w);
    *(f16x4*)(out + (size_t)row * DIM + c) = o;
}

extern "C" void kernel_launch(void* const* d_in, const int* in_sizes, int n_in,
                              void* d_out, int out_size, void* d_ws, size_t ws_size,
                              hipStream_t stream)
{
    const float* x      = (const float*)d_in[0];
    const int* qw       = (const int*)d_in[1];
    const float* scales = (const float*)d_in[2];
    const float* bias   = (const float*)d_in[3];
    const float* la     = (const float*)d_in[4];
    const float* lb     = (const float*)d_in[5];
    const float* g      = (const float*)d_in[6];
    const float* be     = (const float*)d_in[7];
    float* out = (float*)d_out;

    char* ws = (char*)d_ws;
    const size_t WEFF_BYTES = (size_t)NLAYERS * DIM * DIM * 2;  // 37.75 MB
    const size_t ACT_BYTES  = (size_t)MROWS * DIM * 2;          // 33.55 MB
    f16_t* weff = (f16_t*)ws;
    f16_t* hbuf = (f16_t*)(ws + WEFF_BYTES);
    f16_t* t1   = (f16_t*)(ws + WEFF_BYTES + ACT_BYTES);
    f16_t* t2   = (f16_t*)(ws + WEFF_BYTES + 2 * ACT_BYTES);

    prep_weights<<<dim3(NLAYERS * 128), 256, 0, stream>>>(qw, scales, la, lb, weff);
    cvt_f32_f16<<<dim3((MROWS * DIM) / 1024), 256, 0, stream>>>(x, hbuf, MROWS * DIM);

    // scale schedule (exact via ReLU homogeneity + LN scale-invariance):
    //   a1 = (1/16)  * relu(u1)        : sA=1/16,  sB=1/16
    //   a2 = (1/1024)* relu(u2)        : sA=1/64,  sB=1/1024
    //   z  = (1/1024)* (u3 + b + h0)   : sA=1,     sB=1/1024   (LN input)
    //   out=           u3 + b + h0     : sA=1024,  sB=1        (final fp32)
    const dim3 ggrid(256);  // (M/256) * (N/256) = 64 * 4
    for (int blk = 0; blk < 6; ++blk) {
        const int li = blk * 3;
        const size_t w0 = (size_t)li * DIM * DIM;
        gemm_bt<0><<<ggrid, 512, 0, stream>>>(hbuf, weff + w0, bias + (size_t)li * DIM,
                                              nullptr, t1, nullptr, 1.f / 16.f, 1.f / 16.f);
        gemm_bt<0><<<ggrid, 512, 0, stream>>>(t1, weff + w0 + (size_t)DIM * DIM,
                                              bias + (size_t)(li + 1) * DIM, nullptr, t2, nullptr,
                                              1.f / 64.f, 1.f / 1024.f);
        if (blk < 5) {
            gemm_bt<1><<<ggrid, 512, 0, stream>>>(t2, weff + w0 + 2 * (size_t)DIM * DIM,
                                                  bias + (size_t)(li + 2) * DIM, hbuf, t1, nullptr,
                                                  1.f, 1.f / 1024.f);
            ln_kernel<<<dim3(MROWS), 256, 0, stream>>>(t1, hbuf, g + (size_t)blk * DIM,
                                                       be + (size_t)blk * DIM);
        } else {
            gemm_bt<2><<<ggrid, 512, 0, stream>>>(t2, weff + w0 + 2 * (size_t)DIM * DIM,
                                                  bias + (size_t)(li + 2) * DIM, hbuf, nullptr, out,
                                                  1024.f, 1.f);
        }
    }
}